// Round 1
// baseline (51.414 us; speedup 1.0000x reference)
//
#include <hip/hip_runtime.h>
#include <hip/hip_bf16.h>
#include <stdint.h>

// ---------------------------------------------------------------------------
// SupervisedInfoNCELoss, N=8192, D=128, TAF=0.05
// loss = mean_i [ 20 + ln(sum_j exp(logit_ij - 20)) - diag_i ]
// logit_ij = zn_i . bn_j / TAF,  bn = [normalize(z_p); normalize(z_n)]
// Fixed max = 20 (cos sim <= 1) -> no online max needed.
// ---------------------------------------------------------------------------

#define TAF_F 0.05f
constexpr float LOG2E  = 1.4426950408889634f;
constexpr float SCALE  = LOG2E / TAF_F;     // logit->exp2 scale on raw dot
constexpr float OFFSET = -20.0f * LOG2E;    // subtract fixed max 20

constexpr int N_ROWS     = 8192;
constexpr int D_DIM      = 128;
constexpr int TWO_N      = 16384;
constexpr int NJ         = 16;              // column chunks (gridDim.y)
constexpr int JCHUNK     = TWO_N / NJ;      // 1024 columns per block
constexpr int BN_TILE    = 64;              // j-tile staged in LDS
constexpr int BLOCK_ROWS = 256;             // rows per block (4 waves x 64)
constexpr int WAVE_ROWS  = 64;              // rows per wave (4 strips of 16)

typedef __bf16 bf16x8 __attribute__((ext_vector_type(8)));
typedef float  f32x4  __attribute__((ext_vector_type(4)));

#if __has_builtin(__builtin_amdgcn_exp2f)
#define EXP2(x) __builtin_amdgcn_exp2f(x)
#else
#define EXP2(x) exp2f(x)
#endif

// ---------------------------------------------------------------------------
// Kernel 1: per-row normalize -> bf16, plus exact f32 diagonal logit.
// grid = 8192 blocks, 128 threads (one thread per element of the row).
// ---------------------------------------------------------------------------
__global__ void normalize_diag_kernel(const float* __restrict__ z,
                                      const float* __restrict__ zp,
                                      const float* __restrict__ znm,
                                      __bf16* __restrict__ znb,
                                      __bf16* __restrict__ bnb,
                                      float* __restrict__ diag) {
    const int i    = blockIdx.x;
    const int t    = threadIdx.x;   // 0..127
    const int lane = t & 63;
    const int wv   = t >> 6;

    const float vz = z[i * D_DIM + t];
    const float vp = zp[i * D_DIM + t];
    const float vn = znm[i * D_DIM + t];

    float sz = vz * vz, sp = vp * vp, sn = vn * vn, szp = vz * vp;
#pragma unroll
    for (int o = 32; o >= 1; o >>= 1) {
        sz  += __shfl_xor(sz, o);
        sp  += __shfl_xor(sp, o);
        sn  += __shfl_xor(sn, o);
        szp += __shfl_xor(szp, o);
    }
    __shared__ float red[2][4];
    if (lane == 0) { red[wv][0] = sz; red[wv][1] = sp; red[wv][2] = sn; red[wv][3] = szp; }
    __syncthreads();
    sz  = red[0][0] + red[1][0];
    sp  = red[0][1] + red[1][1];
    sn  = red[0][2] + red[1][2];
    szp = red[0][3] + red[1][3];

    const float rz = 1.0f / fmaxf(sqrtf(sz), 1e-8f);
    const float rp = 1.0f / fmaxf(sqrtf(sp), 1e-8f);
    const float rn = 1.0f / fmaxf(sqrtf(sn), 1e-8f);

    znb[i * D_DIM + t]            = (__bf16)(vz * rz);
    bnb[i * D_DIM + t]            = (__bf16)(vp * rp);
    bnb[(N_ROWS + i) * D_DIM + t] = (__bf16)(vn * rn);
    if (t == 0) diag[i] = szp * rz * rp * (1.0f / TAF_F);
}

// ---------------------------------------------------------------------------
// Kernel 2: fused GEMM + partial sum-of-exp.
// grid = (N/256, NJ).  Each wave owns 64 rows (A-frags in registers),
// iterates 16 j-tiles of 64 cols staged in LDS (XOR-swizzled).
// mfma_f32_16x16x32_bf16: A row = lane&15, k = (lane>>4)*8+e;
//                         B col = lane&15, k = (lane>>4)*8+e;
//                         C row = (lane>>4)*4+reg, col = lane&15 (m89).
// ---------------------------------------------------------------------------
__global__ __launch_bounds__(256, 2) void partial_lse_kernel(
        const __bf16* __restrict__ znb,
        const __bf16* __restrict__ bnb,
        float* __restrict__ partial) {
    __shared__ __align__(16) unsigned char lds[BN_TILE * D_DIM * 2];  // 16 KiB

    const int tid  = threadIdx.x;
    const int lane = tid & 63;
    const int wv   = tid >> 6;
    const int l15  = lane & 15;
    const int l4   = lane >> 4;
    const int rowBase = blockIdx.x * BLOCK_ROWS + wv * WAVE_ROWS;
    const int jBase   = blockIdx.y * JCHUNK;

    // A fragments for 4 row-strips x 4 K-steps (held in VGPRs whole kernel)
    bf16x8 a[4][4];
#pragma unroll
    for (int s = 0; s < 4; ++s)
#pragma unroll
        for (int kk = 0; kk < 4; ++kk) {
            const __bf16* p = znb + (size_t)(rowBase + s * 16 + l15) * D_DIM + kk * 32 + l4 * 8;
            a[s][kk] = *reinterpret_cast<const bf16x8*>(p);
        }

    float sums[4][4];
#pragma unroll
    for (int s = 0; s < 4; ++s)
#pragma unroll
        for (int e = 0; e < 4; ++e) sums[s][e] = 0.0f;

    const unsigned char* srcBase = reinterpret_cast<const unsigned char*>(bnb);

    for (int jt = 0; jt < JCHUNK / BN_TILE; ++jt) {
        const int j0 = jBase + jt * BN_TILE;
        // stage 64x128 bf16 (16 KiB = 1024 16B-chunks), XOR swizzle on dest:
        // chunk c = row*16 + kc  ->  lds chunk c ^ ((c>>4)&7)
        const unsigned char* src = srcBase + (size_t)j0 * 256;
#pragma unroll
        for (int it = 0; it < 4; ++it) {
            const int c  = it * 256 + tid;
            const uint4 v = *reinterpret_cast<const uint4*>(src + c * 16);
            const int cd = c ^ ((c >> 4) & 7);
            *reinterpret_cast<uint4*>(lds + cd * 16) = v;
        }
        __syncthreads();

#pragma unroll
        for (int jsub = 0; jsub < 4; ++jsub) {
            bf16x8 b[4];
            const int r = jsub * 16 + l15;   // tile row = output column j
#pragma unroll
            for (int kk = 0; kk < 4; ++kk) {
                const int cl = r * 16 + kk * 4 + l4;   // linear chunk
                const int ca = cl ^ (r & 7);           // swizzled
                b[kk] = *reinterpret_cast<const bf16x8*>(lds + ca * 16);
            }
#pragma unroll
            for (int s = 0; s < 4; ++s) {
                f32x4 acc = {0.0f, 0.0f, 0.0f, 0.0f};
#pragma unroll
                for (int kk = 0; kk < 4; ++kk)
                    acc = __builtin_amdgcn_mfma_f32_16x16x32_bf16(a[s][kk], b[kk], acc, 0, 0, 0);
#pragma unroll
                for (int e = 0; e < 4; ++e)
                    sums[s][e] += EXP2(fmaf(acc[e], SCALE, OFFSET));
            }
        }
        __syncthreads();
    }

    // reduce each running sum over the 16 column-holding lanes (lane&15)
#pragma unroll
    for (int s = 0; s < 4; ++s)
#pragma unroll
        for (int e = 0; e < 4; ++e) {
            float v = sums[s][e];
            v += __shfl_xor(v, 1);
            v += __shfl_xor(v, 2);
            v += __shfl_xor(v, 4);
            v += __shfl_xor(v, 8);
            sums[s][e] = v;
        }
    if (l15 == 0) {
#pragma unroll
        for (int s = 0; s < 4; ++s)
#pragma unroll
            for (int e = 0; e < 4; ++e) {
                const int row = rowBase + s * 16 + l4 * 4 + e;
                partial[(size_t)row * NJ + blockIdx.y] = sums[s][e];
            }
    }
}

// ---------------------------------------------------------------------------
// Kernel 3: per-row merge + ln + diag subtract; per-block partial sums.
// grid = 32 blocks x 256 threads (one thread per row).
// ---------------------------------------------------------------------------
__global__ void finalize_rows_kernel(const float* __restrict__ partial,
                                     const float* __restrict__ diag,
                                     float* __restrict__ blocksum) {
    const int t = threadIdx.x;
    const int r = blockIdx.x * 256 + t;
    float se = 0.0f;
#pragma unroll
    for (int c = 0; c < NJ; ++c) se += partial[(size_t)r * NJ + c];
    float res = 20.0f + logf(se) - diag[r];
#pragma unroll
    for (int o = 32; o >= 1; o >>= 1) res += __shfl_xor(res, o);
    __shared__ float red[4];
    if ((t & 63) == 0) red[t >> 6] = res;
    __syncthreads();
    if (t == 0) blocksum[blockIdx.x] = red[0] + red[1] + red[2] + red[3];
}

// ---------------------------------------------------------------------------
// Kernel 4: final reduce of 32 block sums -> mean -> d_out[0].
// ---------------------------------------------------------------------------
__global__ void final_kernel(const float* __restrict__ blocksum,
                             float* __restrict__ out) {
    const int t = threadIdx.x;  // 64 threads
    float v = (t < 32) ? blocksum[t] : 0.0f;
#pragma unroll
    for (int o = 32; o >= 1; o >>= 1) v += __shfl_xor(v, o);
    if (t == 0) out[0] = v * (1.0f / (float)N_ROWS);
}

// ---------------------------------------------------------------------------
extern "C" void kernel_launch(void* const* d_in, const int* in_sizes, int n_in,
                              void* d_out, int out_size, void* d_ws, size_t ws_size,
                              hipStream_t stream) {
    const float* z   = (const float*)d_in[0];
    const float* zp  = (const float*)d_in[1];
    const float* znm = (const float*)d_in[2];

    char* ws = (char*)d_ws;
    // workspace layout (bytes):
    //   znb     : [8192][128] bf16            @ 0         (2,097,152)
    //   bnb     : [16384][128] bf16           @ 2,097,152 (4,194,304)
    //   diag    : [8192] f32                  @ 6,291,456 (32,768)
    //   partial : [8192][NJ=16] f32           @ 6,324,224 (524,288)
    //   blocksum: [32] f32                    @ 6,848,512 (128)
    __bf16* znb     = (__bf16*)(ws);
    __bf16* bnb     = (__bf16*)(ws + 2097152);
    float*  diag    = (float*)(ws + 6291456);
    float*  partial = (float*)(ws + 6324224);
    float*  blocksum= (float*)(ws + 6848512);
    float*  out     = (float*)d_out;

    normalize_diag_kernel<<<N_ROWS, 128, 0, stream>>>(z, zp, znm, znb, bnb, diag);
    partial_lse_kernel<<<dim3(N_ROWS / BLOCK_ROWS, NJ), 256, 0, stream>>>(znb, bnb, partial);
    finalize_rows_kernel<<<N_ROWS / 256, 256, 0, stream>>>(partial, diag, blocksum);
    final_kernel<<<1, 64, 0, stream>>>(blocksum, out);
}